// Round 1
// baseline (197.103 us; speedup 1.0000x reference)
//
#include <hip/hip_runtime.h>

// tanh(x) = 1 - 2/(exp(2x)+1), using hw v_exp_f32 (computes 2^x) and v_rcp_f32.
// Saturates correctly: x->+inf => e=inf => rcp=0 => 1; x->-inf => e=0 => -1.
__device__ __forceinline__ float fast_tanh(float x) {
    float e = __builtin_amdgcn_exp2f(x * 2.8853900817779268f);
    float r = __builtin_amdgcn_rcpf(e + 1.0f);
    return 1.0f - 2.0f * r;
}

// One sample: 8 input floats x[t*2+d] (t=0..3, d=0..1) -> classifier scalar.
__device__ __forceinline__ float rnn_one(
    const float x[8],
    float w00, float w01, float w10, float w11, float bi0, float bi1,
    float u00, float u01, float u10, float u11, float bh0, float bh1,
    float c0, float c1, float cb)
{
    float h0 = 0.0f, h1 = 0.0f;
#pragma unroll
    for (int t = 0; t < 4; ++t) {
        float xt0 = x[2 * t], xt1 = x[2 * t + 1];
        // ix_t[h] = W_ih[h][0]*x0 + W_ih[h][1]*x1 + b_ih[h]
        float p0 = fmaf(w00, xt0, fmaf(w01, xt1, bi0));
        float p1 = fmaf(w10, xt0, fmaf(w11, xt1, bi1));
        // h_t[h] = tanh(ix_t[h] + W_hh[h][0]*h0 + W_hh[h][1]*h1 + b_hh[h])
        float n0 = fast_tanh(p0 + fmaf(u00, h0, fmaf(u01, h1, bh0)));
        float n1 = fast_tanh(p1 + fmaf(u10, h0, fmaf(u11, h1, bh1)));
        h0 = n0;
        h1 = n1;
    }
    return fmaf(c0, h0, fmaf(c1, h1, cb));
}

// SPT samples per thread: 8 dwordx4 loads in flight per thread (128 B/lane
// contiguous), one dwordx4 output store. MLP >> the old 2-loads-per-thread.
constexpr int SPT = 4;

__global__ __launch_bounds__(256) void rnn2_cls_kernel(
    const float* __restrict__ X,       // [B,4,2]
    const float* __restrict__ w_ih,    // [2,2] row-major: w_ih[h*2+d]
    const float* __restrict__ b_ih,    // [2]
    const float* __restrict__ w_hh,    // [2,2]
    const float* __restrict__ b_hh,    // [2]
    const float* __restrict__ cls_w,   // [1,2]
    const float* __restrict__ cls_b,   // [1]
    float* __restrict__ out,           // [B]
    int B)
{
    const int tid = blockIdx.x * blockDim.x + threadIdx.x;
    const long long s0 = (long long)tid * SPT;
    if (s0 >= B) return;

    // Uniform-address parameter loads: scalar-cached, negligible traffic.
    const float w00 = w_ih[0], w01 = w_ih[1], w10 = w_ih[2], w11 = w_ih[3];
    const float bi0 = b_ih[0], bi1 = b_ih[1];
    const float u00 = w_hh[0], u01 = w_hh[1], u10 = w_hh[2], u11 = w_hh[3];
    const float bh0 = b_hh[0], bh1 = b_hh[1];
    const float c0 = cls_w[0], c1 = cls_w[1], cb = cls_b[0];

    const float4* X4 = reinterpret_cast<const float4*>(X);

    if (s0 + SPT <= B) {
        // Fast path: 8 independent float4 loads issued up front.
        float4 d[2 * SPT];
#pragma unroll
        for (int k = 0; k < 2 * SPT; ++k) d[k] = X4[2 * s0 + k];

        float o[SPT];
#pragma unroll
        for (int s = 0; s < SPT; ++s) {
            float xv[8] = {d[2 * s].x,     d[2 * s].y,     d[2 * s].z,     d[2 * s].w,
                           d[2 * s + 1].x, d[2 * s + 1].y, d[2 * s + 1].z, d[2 * s + 1].w};
            o[s] = rnn_one(xv, w00, w01, w10, w11, bi0, bi1,
                           u00, u01, u10, u11, bh0, bh1, c0, c1, cb);
        }
        // s0 is a multiple of 4 -> 16 B aligned float4 store.
        *reinterpret_cast<float4*>(out + s0) = make_float4(o[0], o[1], o[2], o[3]);
    } else {
        // Tail: per-sample scalar path (only the last partial group).
        for (long long s = s0; s < B; ++s) {
            float4 lo = X4[2 * s];
            float4 hi = X4[2 * s + 1];
            float xv[8] = {lo.x, lo.y, lo.z, lo.w, hi.x, hi.y, hi.z, hi.w};
            out[s] = rnn_one(xv, w00, w01, w10, w11, bi0, bi1,
                             u00, u01, u10, u11, bh0, bh1, c0, c1, cb);
        }
    }
}

extern "C" void kernel_launch(void* const* d_in, const int* in_sizes, int n_in,
                              void* d_out, int out_size, void* d_ws, size_t ws_size,
                              hipStream_t stream) {
    const float* X     = (const float*)d_in[0];
    const float* w_ih  = (const float*)d_in[1];
    const float* b_ih  = (const float*)d_in[2];
    const float* w_hh  = (const float*)d_in[3];
    const float* b_hh  = (const float*)d_in[4];
    const float* cls_w = (const float*)d_in[5];
    const float* cls_b = (const float*)d_in[6];
    float* out = (float*)d_out;

    int B = in_sizes[0] / 8;  // X is [B,4,2]
    int block = 256;
    long long threads = ((long long)B + SPT - 1) / SPT;
    int grid = (int)((threads + block - 1) / block);
    rnn2_cls_kernel<<<grid, block, 0, stream>>>(X, w_ih, b_ih, w_hh, b_hh,
                                                cls_w, cls_b, out, B);
}

// Round 2
// 189.779 us; speedup vs baseline: 1.0386x; 1.0386x over previous
//
#include <hip/hip_runtime.h>

typedef float f4 __attribute__((ext_vector_type(4)));

// tanh(x) = 1 - 2/(exp(2x)+1), using hw v_exp_f32 (computes 2^x) and v_rcp_f32.
// Saturates correctly: x->+inf => e=inf => rcp=0 => 1; x->-inf => e=0 => -1.
__device__ __forceinline__ float fast_tanh(float x) {
    float e = __builtin_amdgcn_exp2f(x * 2.8853900817779268f);
    float r = __builtin_amdgcn_rcpf(e + 1.0f);
    return 1.0f - 2.0f * r;
}

// One thread per sample (SPT=1 — R1 showed SPT=4 regresses; MLP is ample).
// Key change vs R0: NON-TEMPORAL loads/stores. X is read once, out written
// once — nt bypasses LLC allocation, so the kernel stops evicting the dirty
// lines left by the harness's 2x488MiB poison fills (which was costing ~128MB
// of hidden writeback traffic inside our dispatch).
__global__ __launch_bounds__(256) void rnn2_cls_kernel(
    const float* __restrict__ X,       // [B,4,2]
    const float* __restrict__ w_ih,    // [2,2] row-major: w_ih[h*2+d]
    const float* __restrict__ b_ih,    // [2]
    const float* __restrict__ w_hh,    // [2,2]
    const float* __restrict__ b_hh,    // [2]
    const float* __restrict__ cls_w,   // [1,2]
    const float* __restrict__ cls_b,   // [1]
    float* __restrict__ out,           // [B]
    int B)
{
    int b = blockIdx.x * blockDim.x + threadIdx.x;
    if (b >= B) return;

    // Uniform-address parameter loads: scalar-cached, negligible traffic.
    const float w00 = w_ih[0], w01 = w_ih[1], w10 = w_ih[2], w11 = w_ih[3];
    const float bi0 = b_ih[0], bi1 = b_ih[1];
    const float u00 = w_hh[0], u01 = w_hh[1], u10 = w_hh[2], u11 = w_hh[3];
    const float bh0 = b_hh[0], bh1 = b_hh[1];
    const float c0 = cls_w[0], c1 = cls_w[1], cb = cls_b[0];

    // 32 B/lane via two nt float4 loads — coalesced, no LLC allocation.
    const f4* X4 = reinterpret_cast<const f4*>(X);
    f4 lo = __builtin_nontemporal_load(X4 + 2 * b);
    f4 hi = __builtin_nontemporal_load(X4 + 2 * b + 1);
    float x[8] = {lo.x, lo.y, lo.z, lo.w, hi.x, hi.y, hi.z, hi.w};

    float h0 = 0.0f, h1 = 0.0f;
#pragma unroll
    for (int t = 0; t < 4; ++t) {
        float xt0 = x[2 * t], xt1 = x[2 * t + 1];
        // ix_t[h] = W_ih[h][0]*x0 + W_ih[h][1]*x1 + b_ih[h]
        float p0 = fmaf(w00, xt0, fmaf(w01, xt1, bi0));
        float p1 = fmaf(w10, xt0, fmaf(w11, xt1, bi1));
        // h_t[h] = tanh(ix_t[h] + W_hh[h][0]*h0 + W_hh[h][1]*h1 + b_hh[h])
        float n0 = fast_tanh(p0 + fmaf(u00, h0, fmaf(u01, h1, bh0)));
        float n1 = fast_tanh(p1 + fmaf(u10, h0, fmaf(u11, h1, bh1)));
        h0 = n0;
        h1 = n1;
    }
    float o = fmaf(c0, h0, fmaf(c1, h1, cb));
    __builtin_nontemporal_store(o, out + b);
}

extern "C" void kernel_launch(void* const* d_in, const int* in_sizes, int n_in,
                              void* d_out, int out_size, void* d_ws, size_t ws_size,
                              hipStream_t stream) {
    const float* X     = (const float*)d_in[0];
    const float* w_ih  = (const float*)d_in[1];
    const float* b_ih  = (const float*)d_in[2];
    const float* w_hh  = (const float*)d_in[3];
    const float* b_hh  = (const float*)d_in[4];
    const float* cls_w = (const float*)d_in[5];
    const float* cls_b = (const float*)d_in[6];
    float* out = (float*)d_out;

    int B = in_sizes[0] / 8;  // X is [B,4,2]
    int block = 256;
    int grid = (B + block - 1) / block;
    rnn2_cls_kernel<<<grid, block, 0, stream>>>(X, w_ih, b_ih, w_hh, b_hh,
                                                cls_w, cls_b, out, B);
}

// Round 3
// 188.512 us; speedup vs baseline: 1.0456x; 1.0067x over previous
//
#include <hip/hip_runtime.h>

typedef float f4 __attribute__((ext_vector_type(4)));

// tanh(x) = 1 - 2/(exp(2x)+1), using hw v_exp_f32 (computes 2^x) and v_rcp_f32.
// Saturates correctly: x->+inf => e=inf => rcp=0 => 1; x->-inf => e=0 => -1.
__device__ __forceinline__ float fast_tanh(float x) {
    float e = __builtin_amdgcn_exp2f(x * 2.8853900817779268f);
    float r = __builtin_amdgcn_rcpf(e + 1.0f);
    return 1.0f - 2.0f * r;
}

// One thread per sample (SPT=1: R1 showed SPT=4 regresses — per-instr lane
// stride became 128 B, breaking perfect coalescing; SPT=1 is 16 B/lane
// contiguous, ideal).
// R3 change: full streaming cache controls `sc0 sc1 nt` (system scope +
// non-temporal) via inline asm — __builtin_nontemporal only emits `nt`,
// which still allows L2/MALL allocation. X read once, out written once:
// zero reuse, so full bypass stops our 128 MB stream from evicting the
// harness fill/copy dirty lines inside our dispatch window.
__global__ __launch_bounds__(256) void rnn2_cls_kernel(
    const float* __restrict__ X,       // [B,4,2]
    const float* __restrict__ w_ih,    // [2,2] row-major: w_ih[h*2+d]
    const float* __restrict__ b_ih,    // [2]
    const float* __restrict__ w_hh,    // [2,2]
    const float* __restrict__ b_hh,    // [2]
    const float* __restrict__ cls_w,   // [1,2]
    const float* __restrict__ cls_b,   // [1]
    float* __restrict__ out,           // [B]
    int B)
{
    int b = blockIdx.x * blockDim.x + threadIdx.x;
    if (b >= B) return;

    // Uniform-address parameter loads: scalar-cached, negligible traffic.
    const float w00 = w_ih[0], w01 = w_ih[1], w10 = w_ih[2], w11 = w_ih[3];
    const float bi0 = b_ih[0], bi1 = b_ih[1];
    const float u00 = w_hh[0], u01 = w_hh[1], u10 = w_hh[2], u11 = w_hh[3];
    const float bh0 = b_hh[0], bh1 = b_hh[1];
    const float c0 = cls_w[0], c1 = cls_w[1], cb = cls_b[0];

    // 32 B/lane: two dwordx4 loads, system-scope non-temporal (no L2/MALL
    // allocation). waitcnt lives INSIDE the asm block so the compiler cannot
    // hoist consumers above it (outputs are the asm's own results).
    const f4* p = reinterpret_cast<const f4*>(X) + 2 * (size_t)b;
    f4 lo, hi;
    asm volatile(
        "global_load_dwordx4 %0, %2, off sc0 sc1 nt\n\t"
        "global_load_dwordx4 %1, %2, off offset:16 sc0 sc1 nt\n\t"
        "s_waitcnt vmcnt(0)"
        : "=&v"(lo), "=&v"(hi)
        : "v"(p));

    float x[8] = {lo.x, lo.y, lo.z, lo.w, hi.x, hi.y, hi.z, hi.w};

    float h0 = 0.0f, h1 = 0.0f;
#pragma unroll
    for (int t = 0; t < 4; ++t) {
        float xt0 = x[2 * t], xt1 = x[2 * t + 1];
        // ix_t[h] = W_ih[h][0]*x0 + W_ih[h][1]*x1 + b_ih[h]
        float p0 = fmaf(w00, xt0, fmaf(w01, xt1, bi0));
        float p1 = fmaf(w10, xt0, fmaf(w11, xt1, bi1));
        // h_t[h] = tanh(ix_t[h] + W_hh[h][0]*h0 + W_hh[h][1]*h1 + b_hh[h])
        float n0 = fast_tanh(p0 + fmaf(u00, h0, fmaf(u01, h1, bh0)));
        float n1 = fast_tanh(p1 + fmaf(u10, h0, fmaf(u11, h1, bh1)));
        h0 = n0;
        h1 = n1;
    }
    float o = fmaf(c0, h0, fmaf(c1, h1, cb));
    // Streaming store: written once, never re-read by us.
    asm volatile("global_store_dword %0, %1, off sc0 sc1 nt"
                 :: "v"(out + b), "v"(o) : "memory");
}

extern "C" void kernel_launch(void* const* d_in, const int* in_sizes, int n_in,
                              void* d_out, int out_size, void* d_ws, size_t ws_size,
                              hipStream_t stream) {
    const float* X     = (const float*)d_in[0];
    const float* w_ih  = (const float*)d_in[1];
    const float* b_ih  = (const float*)d_in[2];
    const float* w_hh  = (const float*)d_in[3];
    const float* b_hh  = (const float*)d_in[4];
    const float* cls_w = (const float*)d_in[5];
    const float* cls_b = (const float*)d_in[6];
    float* out = (float*)d_out;

    int B = in_sizes[0] / 8;  // X is [B,4,2]
    int block = 256;
    int grid = (B + block - 1) / block;
    rnn2_cls_kernel<<<grid, block, 0, stream>>>(X, w_ih, b_ih, w_hh, b_hh,
                                                cls_w, cls_b, out, B);
}

// Round 4
// 187.095 us; speedup vs baseline: 1.0535x; 1.0076x over previous
//
#include <hip/hip_runtime.h>

typedef float f4 __attribute__((ext_vector_type(4)));

// tanh(x) = 1 - 2/(exp(2x)+1), using hw v_exp_f32 (computes 2^x) and v_rcp_f32.
// Saturates correctly: x->+inf => e=inf => rcp=0 => 1; x->-inf => e=0 => -1.
__device__ __forceinline__ float fast_tanh(float x) {
    float e = __builtin_amdgcn_exp2f(x * 2.8853900817779268f);
    float r = __builtin_amdgcn_rcpf(e + 1.0f);
    return 1.0f - 2.0f * r;
}

__device__ __forceinline__ f4 shfl_xor1(f4 v) {
    f4 r;
    r.x = __shfl_xor(v.x, 1, 64);
    r.y = __shfl_xor(v.y, 1, 64);
    r.z = __shfl_xor(v.z, 1, 64);
    r.w = __shfl_xor(v.w, 1, 64);
    return r;
}

__device__ __forceinline__ float rnn_one(
    const f4 lo, const f4 hi,
    float w00, float w01, float w10, float w11, float bi0, float bi1,
    float u00, float u01, float u10, float u11, float bh0, float bh1,
    float c0, float c1, float cb)
{
    float x[8] = {lo.x, lo.y, lo.z, lo.w, hi.x, hi.y, hi.z, hi.w};
    float h0 = 0.0f, h1 = 0.0f;
#pragma unroll
    for (int t = 0; t < 4; ++t) {
        float xt0 = x[2 * t], xt1 = x[2 * t + 1];
        float p0 = fmaf(w00, xt0, fmaf(w01, xt1, bi0));
        float p1 = fmaf(w10, xt0, fmaf(w11, xt1, bi1));
        float n0 = fast_tanh(p0 + fmaf(u00, h0, fmaf(u01, h1, bh0)));
        float n1 = fast_tanh(p1 + fmaf(u10, h0, fmaf(u11, h1, bh1)));
        h0 = n0;
        h1 = n1;
    }
    return fmaf(c0, h0, fmaf(c1, h1, cb));
}

// R4 change: CONTIGUOUS per-instruction load footprint. Previously each
// thread issued 2 dwordx4 at 32 B lane-stride: each instruction spanned 2 KB
// per wave delivering 1 KB (50% utilization). Under nt NO-ALLOCATE that means
// both instructions fetch the same HBM bursts and discard half => ~2x read
// traffic (256 MB), matching the observed ~38 us kernel time. Now each wave
// loads its 64 samples' 128 consecutive float4s as two fully-contiguous 1 KB
// instructions, then one shfl_xor(1) re-pairs halves: even lane 2k owns
// sample base+k, odd lane 2k+1 owns sample base+32+k. Stores remain one
// contiguous 256 B segment per wave (permuted within - coalescer handles it).
__global__ __launch_bounds__(256) void rnn2_cls_kernel(
    const float* __restrict__ X,       // [B,4,2]
    const float* __restrict__ w_ih,    // [2,2] row-major: w_ih[h*2+d]
    const float* __restrict__ b_ih,    // [2]
    const float* __restrict__ w_hh,    // [2,2]
    const float* __restrict__ b_hh,    // [2]
    const float* __restrict__ cls_w,   // [1,2]
    const float* __restrict__ cls_b,   // [1]
    float* __restrict__ out,           // [B]
    int B)
{
    const int lane = (int)(threadIdx.x & 63);
    const long long wave = (((long long)blockIdx.x * blockDim.x) + threadIdx.x) >> 6;
    const long long sb = wave * 64;    // first sample owned by this wave
    if (sb >= B) return;

    // Uniform-address parameter loads: scalar-cached, negligible traffic.
    const float w00 = w_ih[0], w01 = w_ih[1], w10 = w_ih[2], w11 = w_ih[3];
    const float bi0 = b_ih[0], bi1 = b_ih[1];
    const float u00 = w_hh[0], u01 = w_hh[1], u10 = w_hh[2], u11 = w_hh[3];
    const float bh0 = b_hh[0], bh1 = b_hh[1];
    const float c0 = cls_w[0], c1 = cls_w[1], cb = cls_b[0];

    const f4* X4 = reinterpret_cast<const f4*>(X);

    if (sb + 64 <= B) {
        // Two contiguous 1 KB wave loads: float4s [2*sb+lane] and [2*sb+64+lane].
        const f4* p = X4 + 2 * sb + lane;
        f4 v0, v1;
        asm volatile(
            "global_load_dwordx4 %0, %2, off sc0 sc1 nt\n\t"
            "global_load_dwordx4 %1, %2, off offset:1024 sc0 sc1 nt\n\t"
            "s_waitcnt vmcnt(0)"
            : "=&v"(v0), "=&v"(v1)
            : "v"(p));

        f4 w0 = shfl_xor1(v0);   // partner lane's half of my sample
        f4 w1 = shfl_xor1(v1);

        f4 lo, hi;
        long long s;
        if ((lane & 1) == 0) {   // even lane 2k -> sample sb+k (from v0 pair)
            lo = v0; hi = w0; s = sb + (lane >> 1);
        } else {                 // odd lane 2k+1 -> sample sb+32+k (from v1 pair)
            lo = w1; hi = v1; s = sb + 32 + (lane >> 1);
        }

        float o = rnn_one(lo, hi, w00, w01, w10, w11, bi0, bi1,
                          u00, u01, u10, u11, bh0, bh1, c0, c1, cb);
        asm volatile("global_store_dword %0, %1, off sc0 sc1 nt"
                     :: "v"(out + s), "v"(o) : "memory");
    } else {
        // Tail wave (B % 64 != 0): original per-thread addressing.
        long long s = sb + lane;
        if (s < B) {
            const f4* p = X4 + 2 * s;
            f4 lo, hi;
            asm volatile(
                "global_load_dwordx4 %0, %2, off sc0 sc1 nt\n\t"
                "global_load_dwordx4 %1, %2, off offset:16 sc0 sc1 nt\n\t"
                "s_waitcnt vmcnt(0)"
                : "=&v"(lo), "=&v"(hi)
                : "v"(p));
            float o = rnn_one(lo, hi, w00, w01, w10, w11, bi0, bi1,
                              u00, u01, u10, u11, bh0, bh1, c0, c1, cb);
            asm volatile("global_store_dword %0, %1, off sc0 sc1 nt"
                         :: "v"(out + s), "v"(o) : "memory");
        }
    }
}

extern "C" void kernel_launch(void* const* d_in, const int* in_sizes, int n_in,
                              void* d_out, int out_size, void* d_ws, size_t ws_size,
                              hipStream_t stream) {
    const float* X     = (const float*)d_in[0];
    const float* w_ih  = (const float*)d_in[1];
    const float* b_ih  = (const float*)d_in[2];
    const float* w_hh  = (const float*)d_in[3];
    const float* b_hh  = (const float*)d_in[4];
    const float* cls_w = (const float*)d_in[5];
    const float* cls_b = (const float*)d_in[6];
    float* out = (float*)d_out;

    int B = in_sizes[0] / 8;  // X is [B,4,2]
    long long waves = ((long long)B + 63) / 64;
    long long threads = waves * 64;
    int block = 256;
    int grid = (int)((threads + block - 1) / block);
    rnn2_cls_kernel<<<grid, block, 0, stream>>>(X, w_ih, b_ih, w_hh, b_hh,
                                                cls_w, cls_b, out, B);
}